// Round 6
// baseline (1135.931 us; speedup 1.0000x reference)
//
#include <hip/hip_runtime.h>
#include <math.h>

#define D 64
#define LOG2E 1.44269504088896340736f
#define QSCALE (0.35355339059327373f * LOG2E)

typedef float f32x4 __attribute__((ext_vector_type(4)));
typedef float vf4 __attribute__((ext_vector_type(4)));
typedef short bf16x8 __attribute__((ext_vector_type(8)));
typedef unsigned short ushort_t;

#define MF(a, b, c) __builtin_amdgcn_mfma_f32_16x16x32_bf16(a, b, c, 0, 0, 0)

// ---------- helpers ----------
__device__ __forceinline__ float bcast(float x, int i) {
  return __int_as_float(__builtin_amdgcn_readlane(__float_as_int(x), i));
}
__device__ __forceinline__ float qsum(float x) {  // sum over the 4 quads
  x += __shfl_xor(x, 16);
  x += __shfl_xor(x, 32);
  return x;
}
__device__ __forceinline__ ushort_t f2b(float f) {  // fp32 -> bf16 RTNE
  unsigned int u = __float_as_uint(f);
  unsigned int r = (u + 0x7FFFu + ((u >> 16) & 1u)) >> 16;
  return (ushort_t)r;
}
__device__ __forceinline__ float b2f(short s) {  // bf16 -> fp32
  return __uint_as_float(((unsigned int)(unsigned short)s) << 16);
}
__device__ __forceinline__ f32x4 ld4(const float* __restrict__ p) { return *(const f32x4*)p; }
// monotonic unsigned key encoding for float atomicMax
__device__ __forceinline__ unsigned int fkey(float f) {
  unsigned int b = __float_as_uint(f);
  return (b & 0x80000000u) ? ~b : (b | 0x80000000u);
}
__device__ __forceinline__ float funkey(unsigned int k) {
  return __uint_as_float((k & 0x80000000u) ? (k ^ 0x80000000u) : ~k);
}
// pack two C-tiles (even ct, odd ct) into one x32 B-operand pair
__device__ __forceinline__ bf16x8 mkpair(const f32x4& ce, const f32x4& co) {
  bf16x8 b;
#pragma unroll
  for (int j = 0; j < 4; j++) {
    b[j] = (short)f2b(ce[j]);
    b[4 + j] = (short)f2b(co[j]);
  }
  return b;
}
__device__ __forceinline__ f32x4 unpk(bf16x8 p, int half) {  // half 0 = even ct, 1 = odd ct
  f32x4 r;
#pragma unroll
  for (int j = 0; j < 4; j++) r[j] = b2f(p[half * 4 + j]);
  return r;
}

// transposed-layout LayerNorm: x,y are 16 channel values/lane (4 ct-tiles x 4 rr); stats over 64 ch
__device__ __forceinline__ void lnT(const f32x4 (&x)[4], f32x4 (&y)[4],
                                    const float* __restrict__ g, const float* __restrict__ b,
                                    int quad) {
  float s1 = 0.f, s2 = 0.f;
#pragma unroll
  for (int ct = 0; ct < 4; ct++)
#pragma unroll
    for (int r = 0; r < 4; r++) { s1 += x[ct][r]; s2 += x[ct][r] * x[ct][r]; }
  s1 = qsum(s1);
  s2 = qsum(s2);
  float mean = s1 * 0.015625f;
  float var = s2 * 0.015625f - mean * mean;
  float rs = rsqrtf(var + 1e-5f);
#pragma unroll
  for (int ct = 0; ct < 4; ct++) {
    f32x4 gv = ld4(g + 16 * ct + 4 * quad);
    f32x4 bv = ld4(b + 16 * ct + 4 * quad);
#pragma unroll
    for (int r = 0; r < 4; r++) y[ct][r] = (x[ct][r] - mean) * rs * gv[r] + bv[r];
  }
}

// ---------- zero fill ----------
__global__ void zero_kernel(float4* __restrict__ p, int n4) {
  int t = blockIdx.x * blockDim.x + threadIdx.x;
  if (t < n4) p[t] = make_float4(0.f, 0.f, 0.f, 0.f);
}

// ---------- prep: pack weights as x32 A-frags with the k-slot permutation ----------
// ws float layout: [0..32767] T_iw fp32 (k4-packed, head_transform); [32768..33279] u[8][64];
// (ws+33280) as ushort: A-frag packs:
//   SI@0 SO@12288 W1S@16384 W2S@32768 CI@49152 CO@61440 W1C@65536 W2C@81920 (end 98304)
// For W[Cout][K]: frag = ct*T + t (ct = c>>4, T = K/32, t = k>>5); within frag:
//   lane = quad*16 + m (m = c&15, quad = (k>>2)&3), j = 4*((k>>4)&1) + (k&3)
__global__ void prep_kernel(const float* __restrict__ si, const float* __restrict__ so,
                            const float* __restrict__ w1s, const float* __restrict__ w2s,
                            const float* __restrict__ ci, const float* __restrict__ co,
                            const float* __restrict__ w1c, const float* __restrict__ w2c,
                            const float* __restrict__ iw, const float* __restrict__ av,
                            float* __restrict__ ws) {
  int t = blockIdx.x * blockDim.x + threadIdx.x;
  ushort_t* bw = (ushort_t*)(ws + 33280);
  if (t < 98304) {
    const float* src;
    int base, cs;
    int l = t;
    if      (l < 12288) { src = si;  base = 0;     cs = 6; }
    else if (l < 16384) { src = so;  base = 12288; cs = 6; l -= 12288; }
    else if (l < 32768) { src = w1s; base = 16384; cs = 6; l -= 16384; }
    else if (l < 49152) { src = w2s; base = 32768; cs = 8; l -= 32768; }
    else if (l < 61440) { src = ci;  base = 49152; cs = 6; l -= 49152; }
    else if (l < 65536) { src = co;  base = 61440; cs = 6; l -= 61440; }
    else if (l < 81920) { src = w1c; base = 65536; cs = 6; l -= 65536; }
    else                { src = w2c; base = 81920; cs = 8; l -= 81920; }
    int c = l >> cs, k = l & ((1 << cs) - 1);
    int T = (1 << cs) >> 5;
    int ct = c >> 4, m = c & 15, tt = k >> 5, rem = k & 31;
    int quad = (rem >> 2) & 3;
    int j = (((rem >> 4) & 1) << 2) | (rem & 3);
    bw[base + (size_t)((ct * T + tt) * 64 + quad * 16 + m) * 8 + j] = f2b(src[l]);
  } else if (t < 131072) {
    int l = t - 98304;  // T_iw fp32 k-packed: c 0..511, k 0..63 (for head_transform)
    int c = l >> 6, k = l & 63;
    ws[(k >> 2) * 2048 + c * 4 + (k & 3)] = iw[l];
  } else if (t < 131584) {
    int l = t - 131072;
    int h = l >> 6, k = l & 63;
    float acc = 0.f;
    for (int c = 0; c < 64; c++) acc += av[h * 64 + c] * iw[(h * 64 + c) * 64 + k];
    ws[32768 + h * 64 + k] = acc;
  }
}

// ---------- transposed FF block: inst (f32, [ch][edge] tiles) += FF(LN(inst)) ----------
__device__ __forceinline__ void ffnT(f32x4 (&inst)[4],
                                     const float* __restrict__ g, const float* __restrict__ b,
                                     const bf16x8* __restrict__ W1, const bf16x8* __restrict__ W2,
                                     const float* __restrict__ b1, const float* __restrict__ b2,
                                     int lane, int quad) {
  f32x4 y[4];
  lnT(inst, y, g, b, quad);
  bf16x8 x0 = mkpair(y[0], y[1]), x1 = mkpair(y[2], y[3]);
  bf16x8 Hp[8];
#pragma unroll
  for (int ht = 0; ht < 8; ht++) {
    f32x4 h[2];
#pragma unroll
    for (int u = 0; u < 2; u++) {
      int ct = 2 * ht + u;
      f32x4 c = {0.f, 0.f, 0.f, 0.f};
      c = MF(W1[(ct * 2 + 0) * 64 + lane], x0, c);
      c = MF(W1[(ct * 2 + 1) * 64 + lane], x1, c);
      f32x4 bb = ld4(b1 + 16 * ct + 4 * quad);
#pragma unroll
      for (int r = 0; r < 4; r++) {
        float v = c[r] + bb[r];
        h[u][r] = 0.5f * v * (1.0f + erff(v * 0.70710678118654752440f));
      }
    }
    Hp[ht] = mkpair(h[0], h[1]);
  }
#pragma unroll
  for (int ct = 0; ct < 4; ct++) {
    f32x4 c = {0.f, 0.f, 0.f, 0.f};
#pragma unroll
    for (int t = 0; t < 8; t++) c = MF(W2[(ct * 8 + t) * 64 + lane], Hp[t], c);
    f32x4 bb = ld4(b2 + 16 * ct + 4 * quad);
#pragma unroll
    for (int r = 0; r < 4; r++) inst[ct][r] += c[r] + bb[r];
  }
}

// ---------- per-edge transformer: one wave = 16 edges, register+LDS resident ----------
__global__ __launch_bounds__(64, 1)
void edge_kernel(const float* __restrict__ features, const float* __restrict__ pos_emb,
                 const float* __restrict__ self_in_b, const float* __restrict__ self_out_b,
                 const float* __restrict__ cross_in_b, const float* __restrict__ cross_out_b,
                 const float* __restrict__ sa_ln1_g, const float* __restrict__ sa_ln1_b,
                 const float* __restrict__ sa_ln2_g, const float* __restrict__ sa_ln2_b,
                 const float* __restrict__ ca_ln1_g, const float* __restrict__ ca_ln1_b,
                 const float* __restrict__ ca_ln2_g, const float* __restrict__ ca_ln2_b,
                 const float* __restrict__ sa_ff_b1, const float* __restrict__ sa_ff_b2,
                 const float* __restrict__ ca_ff_b1, const float* __restrict__ ca_ff_b2,
                 const int* __restrict__ midx, const int* __restrict__ dstv,
                 const float* __restrict__ ws,
                 float* __restrict__ inst_out, float* __restrict__ a_out,
                 unsigned int* __restrict__ seg_max, int E, int N) {
  const int lane = threadIdx.x;
  const int quad = lane >> 4, lo = lane & 15;
  const int e0 = blockIdx.x * 16;
  __shared__ float xp[16 * 68];
  // lane-local tokPost slab: slot (s*2+u)*64+lane is written and read only by `lane`
  __shared__ __align__(16) ushort_t tpb[10 * 64 * 8];
  bf16x8* TPB = (bf16x8*)tpb;

  const ushort_t* bw = (const ushort_t*)(ws + 33280);
  const bf16x8* WSI = (const bf16x8*)(bw);
  const bf16x8* WSO = (const bf16x8*)(bw + 12288);
  const bf16x8* W1S = (const bf16x8*)(bw + 16384);
  const bf16x8* W2S = (const bf16x8*)(bw + 32768);
  const bf16x8* WCI = (const bf16x8*)(bw + 49152);
  const bf16x8* WCO = (const bf16x8*)(bw + 61440);
  const bf16x8* W1C = (const bf16x8*)(bw + 65536);
  const bf16x8* W2C = (const bf16x8*)(bw + 81920);
  const float* uvec = ws + 32768;

  // per-lane edge meta: lane (quad, lo) owns edge e0+lo (replicated across quads)
  const bool ge = (e0 + lo) < E;
  const int eIdx = min(e0 + lo, E - 1);
  int ids[5];
#pragma unroll
  for (int s = 0; s < 5; s++) ids[s] = midx[eIdx * 5 + s];
  int vb = 0;
#pragma unroll
  for (int s = 0; s < 5; s++)
    if (ids[s] != N && ge) vb |= (1 << s);
  const int nv = __popc(vb);
  const int lp = max(nv - 1, 0);
  int lid = ids[0];
#pragma unroll
  for (int s = 1; s < 5; s++) lid = (lp == s) ? ids[s] : lid;

  // ---- stage 1: gather + pos + LN(sa_ln1) -> XL pairs (bf16, [ch][edge]) ----
  bf16x8 XL[5][2];
#pragma unroll
  for (int s = 0; s < 5; s++) {
    f32x4 t[4], y[4];
    const bool vd = (vb >> s) & 1;
    const float* fp = features + (size_t)min(ids[s], N - 1) * 64;
#pragma unroll
    for (int ct = 0; ct < 4; ct++) {
      f32x4 f = ld4(fp + 16 * ct + 4 * quad);
      f32x4 p = ld4(pos_emb + s * 64 + 16 * ct + 4 * quad);
#pragma unroll
      for (int r = 0; r < 4; r++) t[ct][r] = vd ? (f[r] + p[r]) : 0.f;
    }
    lnT(t, y, sa_ln1_g, sa_ln1_b, quad);
    XL[s][0] = mkpair(y[0], y[1]);
    XL[s][1] = mkpair(y[2], y[3]);
  }

  // ---- K, V GEMMs (register-resident, bf16-packed) ----
  bf16x8 Kp[5][2], Vp[5][2];
#pragma unroll
  for (int s = 0; s < 5; s++) {
    f32x4 kt[4], vt[4];
#pragma unroll
    for (int ct = 0; ct < 4; ct++) {
      f32x4 c = {0.f, 0.f, 0.f, 0.f};
      c = MF(WSI[((4 + ct) * 2 + 0) * 64 + lane], XL[s][0], c);
      c = MF(WSI[((4 + ct) * 2 + 1) * 64 + lane], XL[s][1], c);
      f32x4 bb = ld4(self_in_b + 64 + 16 * ct + 4 * quad);
#pragma unroll
      for (int r = 0; r < 4; r++) kt[ct][r] = c[r] + bb[r];
      f32x4 c2 = {0.f, 0.f, 0.f, 0.f};
      c2 = MF(WSI[((8 + ct) * 2 + 0) * 64 + lane], XL[s][0], c2);
      c2 = MF(WSI[((8 + ct) * 2 + 1) * 64 + lane], XL[s][1], c2);
      f32x4 bb2 = ld4(self_in_b + 128 + 16 * ct + 4 * quad);
#pragma unroll
      for (int r = 0; r < 4; r++) vt[ct][r] = c2[r] + bb2[r];
    }
    Kp[s][0] = mkpair(kt[0], kt[1]);
    Kp[s][1] = mkpair(kt[2], kt[3]);
    Vp[s][0] = mkpair(vt[0], vt[1]);
    Vp[s][1] = mkpair(vt[2], vt[3]);
  }

  // ---- per-qs: Q GEMM, per-head attention (lane-local + 1 shfl), PV, out-proj, residual, pool ----
  f32x4 pool[4];
#pragma unroll
  for (int ct = 0; ct < 4; ct++) pool[ct] = (f32x4){0.f, 0.f, 0.f, 0.f};
#pragma unroll
  for (int qs = 0; qs < 5; qs++) {
    f32x4 qf[4];
#pragma unroll
    for (int ct = 0; ct < 4; ct++) {
      f32x4 c = {0.f, 0.f, 0.f, 0.f};
      c = MF(WSI[(ct * 2 + 0) * 64 + lane], XL[qs][0], c);
      c = MF(WSI[(ct * 2 + 1) * 64 + lane], XL[qs][1], c);
      f32x4 bb = ld4(self_in_b + 16 * ct + 4 * quad);
#pragma unroll
      for (int r = 0; r < 4; r++) qf[ct][r] = (c[r] + bb[r]) * QSCALE;
    }
    // head h = 2ct + (quad>>1): dot over this lane's 4 ch + partner quad via shfl_xor(16)
    float p[4][5];
#pragma unroll
    for (int ct = 0; ct < 4; ct++) {
      float mx = -3.0e30f;
#pragma unroll
      for (int ks = 0; ks < 5; ks++) {
        f32x4 kv = unpk(Kp[ks][ct >> 1], ct & 1);
        float sp = qf[ct][0] * kv[0] + qf[ct][1] * kv[1] + qf[ct][2] * kv[2] + qf[ct][3] * kv[3];
        sp += __shfl_xor(sp, 16);
        float sv = ((vb >> ks) & 1) ? sp : -1e30f;
        p[ct][ks] = sv;
        mx = fmaxf(mx, sv);
      }
      float sum = 0.f;
#pragma unroll
      for (int ks = 0; ks < 5; ks++) { p[ct][ks] = exp2f(p[ct][ks] - mx); sum += p[ct][ks]; }
      float ri = 1.0f / sum;
#pragma unroll
      for (int ks = 0; ks < 5; ks++) p[ct][ks] *= ri;
    }
    f32x4 o[4];
#pragma unroll
    for (int ct = 0; ct < 4; ct++) {
      o[ct] = (f32x4){0.f, 0.f, 0.f, 0.f};
#pragma unroll
      for (int ks = 0; ks < 5; ks++) {
        f32x4 vv = unpk(Vp[ks][ct >> 1], ct & 1);
#pragma unroll
        for (int r = 0; r < 4; r++) o[ct][r] = fmaf(p[ct][ks], vv[r], o[ct][r]);
      }
    }
    bf16x8 o0 = mkpair(o[0], o[1]), o1 = mkpair(o[2], o[3]);
    // out-proj + residual (re-gather) + masked pool; tokPost -> LDS slab (lane-local)
    const bool vd = (vb >> qs) & 1;
    const float* fp = features + (size_t)min(ids[qs], N - 1) * 64;
    f32x4 tpc[4];
#pragma unroll
    for (int ct = 0; ct < 4; ct++) {
      f32x4 c = {0.f, 0.f, 0.f, 0.f};
      c = MF(WSO[(ct * 2 + 0) * 64 + lane], o0, c);
      c = MF(WSO[(ct * 2 + 1) * 64 + lane], o1, c);
      f32x4 bb = ld4(self_out_b + 16 * ct + 4 * quad);
      f32x4 f = ld4(fp + 16 * ct + 4 * quad);
      f32x4 pp = ld4(pos_emb + qs * 64 + 16 * ct + 4 * quad);
#pragma unroll
      for (int r = 0; r < 4; r++) {
        float tokr = vd ? (f[r] + pp[r]) : 0.f;
        float tp = c[r] + bb[r] + tokr;
        tpc[ct][r] = tp;
        pool[ct][r] += vd ? tp : 0.f;
      }
    }
    TPB[(qs * 2 + 0) * 64 + lane] = mkpair(tpc[0], tpc[1]);
    TPB[(qs * 2 + 1) * 64 + lane] = mkpair(tpc[2], tpc[3]);
  }

  f32x4 inst[4];
  {
    float rn = 1.0f / (float)max(nv, 1);
#pragma unroll
    for (int ct = 0; ct < 4; ct++)
#pragma unroll
      for (int r = 0; r < 4; r++) inst[ct][r] = pool[ct][r] * rn;
  }

  // ---- FF-sa ----
  ffnT(inst, sa_ln2_g, sa_ln2_b, W1S, W2S, sa_ff_b1, sa_ff_b2, lane, quad);

  // ---- cross attention ----
  {
    f32x4 tf[4], xq[4];
    const bool vdl = lid != N;
    const float* fp = features + (size_t)min(lid, N - 1) * 64;
#pragma unroll
    for (int ct = 0; ct < 4; ct++) {
      f32x4 f = ld4(fp + 16 * ct + 4 * quad);
#pragma unroll
      for (int r = 0; r < 4; r++) tf[ct][r] = vdl ? f[r] : 0.f;
    }
    lnT(tf, xq, ca_ln1_g, ca_ln1_b, quad);
    bf16x8 xq0 = mkpair(xq[0], xq[1]), xq1 = mkpair(xq[2], xq[3]);
    f32x4 qcf[4];
#pragma unroll
    for (int ct = 0; ct < 4; ct++) {
      f32x4 c = {0.f, 0.f, 0.f, 0.f};
      c = MF(WCI[(ct * 2 + 0) * 64 + lane], xq0, c);
      c = MF(WCI[(ct * 2 + 1) * 64 + lane], xq1, c);
      f32x4 bb = ld4(cross_in_b + 16 * ct + 4 * quad);
#pragma unroll
      for (int r = 0; r < 4; r++) qcf[ct][r] = (c[r] + bb[r]) * QSCALE;
    }
    bf16x8 Kc[5][2], Vc[5][2];
#pragma unroll
    for (int s = 0; s < 5; s++) {
      bf16x8 tp0 = TPB[(s * 2 + 0) * 64 + lane];
      bf16x8 tp1 = TPB[(s * 2 + 1) * 64 + lane];
      f32x4 kt[4], vt[4];
#pragma unroll
      for (int ct = 0; ct < 4; ct++) {
        f32x4 c = {0.f, 0.f, 0.f, 0.f};
        c = MF(WCI[((4 + ct) * 2 + 0) * 64 + lane], tp0, c);
        c = MF(WCI[((4 + ct) * 2 + 1) * 64 + lane], tp1, c);
        f32x4 bb = ld4(cross_in_b + 64 + 16 * ct + 4 * quad);
#pragma unroll
        for (int r = 0; r < 4; r++) kt[ct][r] = c[r] + bb[r];
        f32x4 c2 = {0.f, 0.f, 0.f, 0.f};
        c2 = MF(WCI[((8 + ct) * 2 + 0) * 64 + lane], tp0, c2);
        c2 = MF(WCI[((8 + ct) * 2 + 1) * 64 + lane], tp1, c2);
        f32x4 bb2 = ld4(cross_in_b + 128 + 16 * ct + 4 * quad);
#pragma unroll
        for (int r = 0; r < 4; r++) vt[ct][r] = c2[r] + bb2[r];
      }
      Kc[s][0] = mkpair(kt[0], kt[1]);
      Kc[s][1] = mkpair(kt[2], kt[3]);
      Vc[s][0] = mkpair(vt[0], vt[1]);
      Vc[s][1] = mkpair(vt[2], vt[3]);
    }
    float p[4][5];
#pragma unroll
    for (int ct = 0; ct < 4; ct++) {
      float mx = -3.0e30f;
#pragma unroll
      for (int ks = 0; ks < 5; ks++) {
        f32x4 kv = unpk(Kc[ks][ct >> 1], ct & 1);
        float sp = qcf[ct][0] * kv[0] + qcf[ct][1] * kv[1] + qcf[ct][2] * kv[2] + qcf[ct][3] * kv[3];
        sp += __shfl_xor(sp, 16);
        float sv = ((vb >> ks) & 1) ? sp : -1e30f;
        p[ct][ks] = sv;
        mx = fmaxf(mx, sv);
      }
      float sum = 0.f;
#pragma unroll
      for (int ks = 0; ks < 5; ks++) { p[ct][ks] = exp2f(p[ct][ks] - mx); sum += p[ct][ks]; }
      float ri = 1.0f / sum;
#pragma unroll
      for (int ks = 0; ks < 5; ks++) p[ct][ks] *= ri;
    }
    f32x4 co[4];
#pragma unroll
    for (int ct = 0; ct < 4; ct++) {
      co[ct] = (f32x4){0.f, 0.f, 0.f, 0.f};
#pragma unroll
      for (int ks = 0; ks < 5; ks++) {
        f32x4 vv = unpk(Vc[ks][ct >> 1], ct & 1);
#pragma unroll
        for (int r = 0; r < 4; r++) co[ct][r] = fmaf(p[ct][ks], vv[r], co[ct][r]);
      }
    }
    bf16x8 c0 = mkpair(co[0], co[1]), c1 = mkpair(co[2], co[3]);
#pragma unroll
    for (int ct = 0; ct < 4; ct++) {
      f32x4 c = {0.f, 0.f, 0.f, 0.f};
      c = MF(WCO[(ct * 2 + 0) * 64 + lane], c0, c);
      c = MF(WCO[(ct * 2 + 1) * 64 + lane], c1, c);
      f32x4 bb = ld4(cross_out_b + 16 * ct + 4 * quad);
#pragma unroll
      for (int r = 0; r < 4; r++) inst[ct][r] += c[r] + bb[r];
    }
  }

  // ---- FF-ca ----
  ffnT(inst, ca_ln2_g, ca_ln2_b, W1C, W2C, ca_ff_b1, ca_ff_b2, lane, quad);

  // ---- a-scores: a[e][h] = leakyrelu(inst . u_h) ----
  float a8[8];
#pragma unroll
  for (int h = 0; h < 8; h++) {
    float sp = 0.f;
#pragma unroll
    for (int ct = 0; ct < 4; ct++) {
      f32x4 uu = ld4(uvec + h * 64 + 16 * ct + 4 * quad);
#pragma unroll
      for (int r = 0; r < 4; r++) sp = fmaf(inst[ct][r], uu[r], sp);
    }
    sp = qsum(sp);
    a8[h] = sp > 0.f ? sp : 0.01f * sp;
  }
  if (ge) {
    int dd = dstv[e0 + lo];
    float v0 = quad == 0 ? a8[0] : quad == 1 ? a8[2] : quad == 2 ? a8[4] : a8[6];
    float v1 = quad == 0 ? a8[1] : quad == 1 ? a8[3] : quad == 2 ? a8[5] : a8[7];
    atomicMax(&seg_max[dd * 8 + 2 * quad], fkey(v0));
    atomicMax(&seg_max[dd * 8 + 2 * quad + 1], fkey(v1));
    if (quad < 2) {
      f32x4 st = (quad == 0) ? (f32x4){a8[0], a8[1], a8[2], a8[3]}
                             : (f32x4){a8[4], a8[5], a8[6], a8[7]};
      *(f32x4*)(a_out + (size_t)(e0 + lo) * 8 + 4 * quad) = st;
    }
  }

  // ---- inst_out: small LDS transpose ([ch][edge] -> [edge][ch]) + coalesced store ----
#pragma unroll
  for (int ct = 0; ct < 4; ct++)
    *(f32x4*)(&xp[lo * 68 + 16 * ct + 4 * quad]) = inst[ct];
  __syncthreads();
  {
    int er = lane >> 2, cb = (lane & 3) * 16;
    if (e0 + er < E) {
#pragma unroll
      for (int u = 0; u < 4; u++) {
        f32x4 v = *(const f32x4*)(&xp[er * 68 + cb + 4 * u]);
        *(f32x4*)(inst_out + (size_t)(e0 + er) * 64 + cb + 4 * u) = v;
      }
    }
  }
}

// ---------- scatter UNNORMALIZED exp-weighted inst_emb into d_out + seg_sum atomics ----------
__global__ __launch_bounds__(256)
void scatter_kernel(const float* __restrict__ inst_emb, const float* __restrict__ a,
                    const unsigned int* __restrict__ seg_max, float* __restrict__ seg_sum,
                    const int* __restrict__ dstv, float* __restrict__ out, int E) {
  const int wid = (blockIdx.x * blockDim.x + threadIdx.x) >> 6;
  const int lane = threadIdx.x & 63;
  if (wid >= E) return;
  int dd = dstv[wid];
  float iv = inst_emb[(size_t)wid * D + lane];
#pragma unroll
  for (int h = 0; h < 8; h++) {
    float m = funkey(seg_max[dd * 8 + h]);
    float ex = __expf(a[(size_t)wid * 8 + h] - m);
    if (lane == h) atomicAdd(&seg_sum[dd * 8 + h], ex);
    atomicAdd(&out[(size_t)dd * 512 + h * 64 + lane], ex * iv);
  }
}

// ---------- per-(n,h): row = inst_w_h @ (row / seg_sum[n,h]), 4 nodes per wave ----------
__global__ __launch_bounds__(256)
void head_transform_kernel(const float* __restrict__ T_iw, const float* __restrict__ seg_sum,
                           float* __restrict__ out, int N) {
  const int wid = (blockIdx.x * blockDim.x + threadIdx.x) >> 6;
  const int lane = threadIdx.x & 63;
  const int h = wid & 7;
  const int n0 = (wid >> 3) * 4;
  if (n0 >= N) return;
  float z[4], acc[4];
#pragma unroll
  for (int j = 0; j < 4; j++) {
    float s = (n0 + j < N) ? seg_sum[(size_t)(n0 + j) * 8 + h] : 0.f;
    float rs = s > 0.f ? 1.0f / s : 0.f;
    z[j] = (n0 + j < N) ? out[((size_t)(n0 + j) * 8 + h) * D + lane] * rs : 0.f;
    acc[j] = 0.f;
  }
  const vf4* P = (const vf4*)T_iw;
  for (int k4 = 0; k4 < 16; k4++) {
    vf4 w = P[k4 * 512 + h * 64 + lane];
#pragma unroll
    for (int u = 0; u < 4; u++) {
      int i = k4 * 4 + u;
#pragma unroll
      for (int j = 0; j < 4; j++) acc[j] = fmaf(bcast(z[j], i), w[u], acc[j]);
    }
  }
#pragma unroll
  for (int j = 0; j < 4; j++)
    if (n0 + j < N) out[((size_t)(n0 + j) * 8 + h) * D + lane] = acc[j];
}

extern "C" void kernel_launch(void* const* d_in, const int* in_sizes, int n_in,
                              void* d_out, int out_size, void* d_ws, size_t ws_size,
                              hipStream_t stream) {
  const float* features   = (const float*)d_in[0];
  const float* pos_emb    = (const float*)d_in[1];
  const float* self_in_w  = (const float*)d_in[2];
  const float* self_in_b  = (const float*)d_in[3];
  const float* self_out_w = (const float*)d_in[4];
  const float* self_out_b = (const float*)d_in[5];
  const float* cross_in_w = (const float*)d_in[6];
  const float* cross_in_b = (const float*)d_in[7];
  const float* cross_out_w= (const float*)d_in[8];
  const float* cross_out_b= (const float*)d_in[9];
  const float* sa_ln1_g = (const float*)d_in[10];
  const float* sa_ln1_b = (const float*)d_in[11];
  const float* sa_ln2_g = (const float*)d_in[12];
  const float* sa_ln2_b = (const float*)d_in[13];
  const float* ca_ln1_g = (const float*)d_in[14];
  const float* ca_ln1_b = (const float*)d_in[15];
  const float* ca_ln2_g = (const float*)d_in[16];
  const float* ca_ln2_b = (const float*)d_in[17];
  const float* sa_ff_w1 = (const float*)d_in[18];
  const float* sa_ff_b1 = (const float*)d_in[19];
  const float* sa_ff_w2 = (const float*)d_in[20];
  const float* sa_ff_b2 = (const float*)d_in[21];
  const float* ca_ff_w1 = (const float*)d_in[22];
  const float* ca_ff_b1 = (const float*)d_in[23];
  const float* ca_ff_w2 = (const float*)d_in[24];
  const float* ca_ff_b2 = (const float*)d_in[25];
  const float* inst_w   = (const float*)d_in[26];
  const float* attn_vec = (const float*)d_in[27];
  const int* midx = (const int*)d_in[28];
  const int* dstv = (const int*)d_in[29];

  const int N = in_sizes[0] / 64;
  const int E = in_sizes[29];

  // ws floats: [0..32767] T_iw | [32768..33279] u | [33280..82431] bf16 A-frag packs
  //            [131072...] inst_emb[E*64] | a[E*8] | seg_max[N*8] | seg_sum[N*8]
  float* wsf = (float*)d_ws;
  float* inst_emb = wsf + 131072;
  float* a_arr = inst_emb + (size_t)E * 64;
  unsigned int* seg_max = (unsigned int*)(a_arr + (size_t)E * 8);
  float* seg_sum = (float*)(seg_max + (size_t)N * 8);

  {
    int n4 = out_size / 4;
    zero_kernel<<<(n4 + 255) / 256, 256, 0, stream>>>((float4*)d_out, n4);
    int s4 = (N * 16) / 4;  // seg_max + seg_sum contiguous
    zero_kernel<<<(s4 + 255) / 256, 256, 0, stream>>>((float4*)seg_max, s4);
  }

  prep_kernel<<<(131584 + 255) / 256, 256, 0, stream>>>(
      self_in_w, self_out_w, sa_ff_w1, sa_ff_w2, cross_in_w, cross_out_w, ca_ff_w1, ca_ff_w2,
      inst_w, attn_vec, wsf);

  int nblk = (E + 15) / 16;  // 1 wave/block, 16 edges/wave
  edge_kernel<<<nblk, 64, 0, stream>>>(
      features, pos_emb, self_in_b, self_out_b, cross_in_b, cross_out_b, sa_ln1_g, sa_ln1_b,
      sa_ln2_g, sa_ln2_b, ca_ln1_g, ca_ln1_b, ca_ln2_g, ca_ln2_b, sa_ff_b1, sa_ff_b2, ca_ff_b1,
      ca_ff_b2, midx, dstv, wsf, inst_emb, a_arr, seg_max, E, N);

  scatter_kernel<<<(E + 3) / 4, 256, 0, stream>>>(inst_emb, a_arr, seg_max, seg_sum, dstv,
                                                  (float*)d_out, E);

  int hwave = ((N + 3) / 4) * 8;
  head_transform_kernel<<<(hwave + 3) / 4, 256, 0, stream>>>(wsf, seg_sum, (float*)d_out, N);
}